// Round 9
// baseline (983.673 us; speedup 1.0000x reference)
//
#include <hip/hip_runtime.h>
#include <hip/hip_bf16.h>
#include <math.h>

#define C 128
#define BSH 9
#define BW (1 << BSH)          // 512-row dst range per bucket

typedef __attribute__((ext_vector_type(8))) short bfrag8;   // 8 bf16 = 4 VGPR
typedef __attribute__((ext_vector_type(4))) float f32x4;

// ---- bf16 helpers ----
__device__ __forceinline__ float bf2f(unsigned short u) {
    union { unsigned int i; float f; } v; v.i = ((unsigned int)u) << 16; return v.f;
}
__device__ __forceinline__ unsigned short f2bf(float f) {
    union { float f; unsigned int i; } u; u.f = f;
    const unsigned int r = u.i + 0x7FFFu + ((u.i >> 16) & 1u);   // RNE
    return (unsigned short)(r >> 16);
}

// ---- dual-dtype input loaders ----
__device__ __forceinline__ float ldin(const void* p, size_t i, int bf) {
    return bf ? bf2f(((const unsigned short*)p)[i]) : ((const float*)p)[i];
}
__device__ __forceinline__ float4 ldin4(const void* p, size_t i, int bf) {
    float4 r;
    if (bf) {
        const ushort4 u = *(const ushort4*)((const unsigned short*)p + i);
        r.x = bf2f(u.x); r.y = bf2f(u.y); r.z = bf2f(u.z); r.w = bf2f(u.w);
    } else {
        r = *(const float4*)((const float*)p + i);
    }
    return r;
}

__device__ __forceinline__ float sigm(float x) { return 1.f / (1.f + expf(-x)); }

// ---------------------------------------------------------------------------
// bf16 MFMA GEMM, 128x128 tile, 4 waves (2x2), 16x16x32, BK=32, LDS stride 40.
//  ASRC: 0 plain A; 1 A'=A*rs[i]+cb[k]; 2 A'=[nf|cos(ts*f+ph)]; 3 A'=[A*rs+cb | xpv]
//  AMODE: 0 ext-f32(dual), 1 int-f32, 2 int-bf16     (A source dtype)
//  BMODE: 0 ext-f32(dual), 1 int-bf16                (B source dtype)
//  BIASM: 0 ext(dual), 1 int-f32
//  EPI:   0 plain store; 1 GRU+relu -> Cout(bf16)+outf(f32); 2 GRU+skip -> Cout(f32)+BN stats
// ---------------------------------------------------------------------------
template <int K, int M, int ASRC, int AMODE, int BMODE, int BIASM, int EPI,
          bool ROWSCALE, bool OUT_BF16>
__global__ __launch_bounds__(256) void gemm_mfma(
    const void* __restrict__ A, const void* __restrict__ Bw,
    const void* __restrict__ bias, void* __restrict__ Cout, int Nrows,
    const float* __restrict__ rs, const void* __restrict__ cb,
    const void* __restrict__ xpv, const void* __restrict__ freq,
    const void* __restrict__ phase, const int* __restrict__ dtf,
    int boff, int bias_off,
    const unsigned short* __restrict__ g1, const void* __restrict__ hp,
    const unsigned short* __restrict__ skipb, float* __restrict__ outf,
    float* __restrict__ bnacc)
{
    __shared__ __align__(16) unsigned short At[128 * 40];
    __shared__ __align__(16) unsigned short Bt[128 * 40];
    __shared__ float bnS[256];

    const int bf = *dtf;
    const int t  = threadIdx.x;
    const int r0 = blockIdx.x * 128;
    const int c0 = blockIdx.y * 128;

    if (EPI == 2 && t < 256) bnS[t] = 0.f;

    const int lane = t & 63, rl = lane & 15, g = lane >> 4;
    const int wid = t >> 6, wr = wid >> 1, wc = wid & 1;

    f32x4 acc[4][4];
#pragma unroll
    for (int m = 0; m < 4; ++m)
#pragma unroll
        for (int n = 0; n < 4; ++n) acc[m][n] = (f32x4){0.f, 0.f, 0.f, 0.f};

    const int sr = t >> 1;
    const int h  = t & 1;
    // h_n column block of the fused gate GEMM: k<128 weights are exactly zero
    const int kstart = (ASRC == 3 && blockIdx.y == 2) ? 128 : 0;

    for (int k0 = kstart; k0 < K; k0 += 32) {
        if (k0 != kstart) __syncthreads();
        const int kb = k0 + h * 16;
        // ---- stage A tile ----
        {
            union { unsigned short u[16]; bfrag8 v[2]; } cv;
            const int grow = r0 + sr;
            if (grow < Nrows) {
                if (ASRC == 2 && kb >= 128) {
                    const float tv = ldin(xpv, grow, bf);
#pragma unroll
                    for (int i = 0; i < 16; ++i)
                        cv.u[i] = f2bf(cosf(tv * ldin(freq, kb - 128 + i, bf) + ldin(phase, kb - 128 + i, bf)));
                } else if (ASRC == 3 && kb >= 128) {
#pragma unroll
                    for (int q = 0; q < 4; ++q) {
                        const float4 v = ldin4(xpv, (size_t)grow * 128 + kb - 128 + 4 * q, bf);
                        cv.u[4 * q + 0] = f2bf(v.x); cv.u[4 * q + 1] = f2bf(v.y);
                        cv.u[4 * q + 2] = f2bf(v.z); cv.u[4 * q + 3] = f2bf(v.w);
                    }
                } else if (AMODE == 2) {
                    const unsigned short* ap = (const unsigned short*)A + (size_t)grow * K + kb;
                    cv.v[0] = *(const bfrag8*)ap;
                    cv.v[1] = *(const bfrag8*)(ap + 8);
                } else {
                    const int AS = (ASRC == 2 || ASRC == 3) ? 128 : K;
                    float vals[16];
#pragma unroll
                    for (int q = 0; q < 4; ++q) {
                        float4 v;
                        if (AMODE == 0) v = ldin4(A, (size_t)grow * AS + kb + 4 * q, bf);
                        else v = *(const float4*)((const float*)A + (size_t)grow * AS + kb + 4 * q);
                        vals[4 * q + 0] = v.x; vals[4 * q + 1] = v.y;
                        vals[4 * q + 2] = v.z; vals[4 * q + 3] = v.w;
                    }
                    if (ASRC == 1 || ASRC == 3) {
                        const float rr = rs[grow];
#pragma unroll
                        for (int i = 0; i < 16; ++i) vals[i] = vals[i] * rr + ldin(cb, kb + i, bf);
                    }
#pragma unroll
                    for (int i = 0; i < 16; ++i) cv.u[i] = f2bf(vals[i]);
                }
            } else {
#pragma unroll
                for (int i = 0; i < 16; ++i) cv.u[i] = 0;
            }
            *(bfrag8*)&At[sr * 40 + h * 16]     = cv.v[0];
            *(bfrag8*)&At[sr * 40 + h * 16 + 8] = cv.v[1];
        }
        // ---- stage B tile (weight rows boff+c0.., k kb..kb+15) ----
        {
            union { unsigned short u[16]; bfrag8 v[2]; } cv;
            const int gcol = boff + c0 + sr;
            if (BMODE == 1) {
                const unsigned short* bp = (const unsigned short*)Bw + (size_t)gcol * K + kb;
                cv.v[0] = *(const bfrag8*)bp;
                cv.v[1] = *(const bfrag8*)(bp + 8);
            } else {
#pragma unroll
                for (int q = 0; q < 4; ++q) {
                    const float4 v = ldin4(Bw, (size_t)gcol * K + kb + 4 * q, bf);
                    cv.u[4 * q + 0] = f2bf(v.x); cv.u[4 * q + 1] = f2bf(v.y);
                    cv.u[4 * q + 2] = f2bf(v.z); cv.u[4 * q + 3] = f2bf(v.w);
                }
            }
            *(bfrag8*)&Bt[sr * 40 + h * 16]     = cv.v[0];
            *(bfrag8*)&Bt[sr * 40 + h * 16 + 8] = cv.v[1];
        }
        __syncthreads();

        bfrag8 a[4], b[4];
#pragma unroll
        for (int m = 0; m < 4; ++m) a[m] = *(const bfrag8*)&At[(wr * 64 + m * 16 + rl) * 40 + g * 8];
#pragma unroll
        for (int n = 0; n < 4; ++n) b[n] = *(const bfrag8*)&Bt[(wc * 64 + n * 16 + rl) * 40 + g * 8];
#pragma unroll
        for (int m = 0; m < 4; ++m)
#pragma unroll
            for (int n = 0; n < 4; ++n)
                acc[m][n] = __builtin_amdgcn_mfma_f32_16x16x32_bf16(a[m], b[n], acc[m][n], 0, 0, 0);
    }

    // ---- epilogue: D row=(lane>>4)*4+reg, col=lane&15 ----
#pragma unroll
    for (int m = 0; m < 4; ++m)
#pragma unroll
        for (int q = 0; q < 4; ++q) {
            const int grow = r0 + wr * 64 + m * 16 + g * 4 + q;
            if (grow < Nrows) {
                const float rsc = ROWSCALE ? rs[grow] : 1.f;
#pragma unroll
                for (int n = 0; n < 4; ++n) {
                    const int gcol = c0 + wc * 64 + n * 16 + rl;
                    float v = acc[m][n][q];
                    if (bias) {
                        v += (BIASM == 1) ? ((const float*)bias)[bias_off + gcol]
                                          : ldin(bias, bias_off + gcol, bf);
                    }
                    if (EPI == 0) {
                        if (ROWSCALE) v *= rsc;
                        if (OUT_BF16) ((unsigned short*)Cout)[(size_t)grow * M + gcol] = f2bf(v);
                        else          ((float*)Cout)[(size_t)grow * M + gcol] = v;
                    } else {
                        // v = i_n[grow,gcol]; combine full GRU from G1=[rsum|zsum|h_n]
                        const size_t gb = (size_t)grow * 384;
                        const size_t p  = (size_t)grow * C + gcol;
                        const float r  = sigm(bf2f(g1[gb + gcol]));
                        const float z  = sigm(bf2f(g1[gb + 128 + gcol]));
                        const float hn = bf2f(g1[gb + 256 + gcol]);
                        const float nn = tanhf(v + r * hn);
                        float o = (1.f - z) * nn + z * ldin(hp, p, bf);
                        if (EPI == 1) {
                            o = fmaxf(o, 0.f);
                            ((unsigned short*)Cout)[p] = f2bf(o);
                            outf[p] = o;
                        } else {
                            o += bf2f(skipb[p]);
                            ((float*)Cout)[p] = o;
                            atomicAdd(&bnS[gcol], o);
                            atomicAdd(&bnS[128 + gcol], o * o);
                        }
                    }
                }
            }
        }
    if (EPI == 2) {
        __syncthreads();
        if (t < 128) {
            atomicAdd(&bnacc[t], bnS[t]);
            atomicAdd(&bnacc[128 + t], bnS[128 + t]);
        }
    }
}

// ---------------------------------------------------------------------------
// prep: Wcat[384,256] bf16 = [[Wih_r|Whh_r],[Wih_z|Whh_z],[0|Whh_n]];
//       biascat[384] f32 = [bih_r+bhh_r, bih_z+bhh_z, bhh_n]
__global__ void prep_kernel(const void* __restrict__ Wih, const void* __restrict__ Whh,
                            const void* __restrict__ bih, const void* __restrict__ bhh,
                            unsigned short* __restrict__ Wcat, float* __restrict__ biascat,
                            const int* __restrict__ dtf)
{
    const int bf = *dtf;
    const int j = blockIdx.x;      // 0..383
    const int k = threadIdx.x;     // 0..255
    float v;
    if (k < 128) v = (j < 256) ? ldin(Wih, (size_t)j * 128 + k, bf) : 0.f;
    else         v = ldin(Whh, (size_t)j * 128 + (k - 128), bf);
    Wcat[(size_t)j * 256 + k] = f2bf(v);
    if (k == 0)
        biascat[j] = (j < 256) ? ldin(bih, j, bf) + ldin(bhh, j, bf) : ldin(bhh, j, bf);
}

// ---------------------------------------------------------------------------
__global__ void probe_kernel(const int* __restrict__ ei,
                             const unsigned int* __restrict__ bfq,
                             int* __restrict__ eflag, int* __restrict__ dtflag)
{
    if (blockIdx.x == 0 && threadIdx.x == 0) {
        int allz = 1;
        for (int i = 0; i < 64; ++i)
            if (ei[2 * i + 1] != 0) { allz = 0; break; }
        *eflag = allz;
        *dtflag = (bfq[0] == 0x3F800000u) ? 0 : 1;
    }
}

__device__ __forceinline__ int edge_src(const int* ei, int E, int e, int i64)
{ return i64 ? ei[2 * e] : ei[e]; }
__device__ __forceinline__ int edge_dst(const int* ei, int E, int e, int i64)
{ return i64 ? ei[2 * E + 2 * e] : ei[E + e]; }

__global__ void init_kernel(int* __restrict__ gcur, float* __restrict__ bn)
{
    const int i = threadIdx.x;
    if (i < 128) gcur[i] = 0;
    bn[i] = 0.0f;
}

// --- K1: partition edges into dst-range buckets (packed (dloc<<17)|src) ---
__global__ __launch_bounds__(256) void part_kernel(
    const int* __restrict__ ei, int E, int cap,
    int* __restrict__ gcur, int* __restrict__ bucketbuf,
    const int* __restrict__ eflag)
{
    __shared__ int hist[128];
    __shared__ int resv[128];
    const int i64 = *eflag;
    const int t = threadIdx.x;
    const int chunk = (E + gridDim.x - 1) / gridDim.x;
    const int e0 = blockIdx.x * chunk;
    const int e1 = min(e0 + chunk, E);
    if (t < 128) hist[t] = 0;
    __syncthreads();
    for (int e = e0 + t; e < e1; e += 256)
        atomicAdd(&hist[edge_dst(ei, E, e, i64) >> BSH], 1);
    __syncthreads();
    if (t < 128) {
        const int c = hist[t];
        resv[t] = c ? atomicAdd(&gcur[t], c) : 0;
        hist[t] = 0;
    }
    __syncthreads();
    for (int e = e0 + t; e < e1; e += 256) {
        const int d = edge_dst(ei, E, e, i64);
        const int s = edge_src(ei, E, e, i64);
        const int b = d >> BSH;
        const int r = atomicAdd(&hist[b], 1);
        bucketbuf[(size_t)b * cap + resv[b] + r] = ((d & (BW - 1)) << 17) | s;
    }
}

// --- K2: per-bucket local CSR ---
__global__ __launch_bounds__(512) void bucket_csr_kernel(
    const int* __restrict__ bucketbuf, const int* __restrict__ gcur,
    int cap, int nb, int N, int E,
    int* __restrict__ rowptr, int* __restrict__ col,
    float* __restrict__ dinv)
{
    __shared__ int hist[BW];
    __shared__ int scn[BW];
    __shared__ int fillc[BW];
    __shared__ int prefix_s;
    const int b = blockIdx.x;
    const int t = threadIdx.x;
    const int Mb = gcur[b];
    const int* eb = bucketbuf + (size_t)b * cap;

    hist[t] = 0; fillc[t] = 0;
    __syncthreads();
    for (int j = t; j < Mb; j += 512) atomicAdd(&hist[eb[j] >> 17], 1);
    __syncthreads();

    const int r0 = b << BSH;
    if (r0 + t < N) dinv[r0 + t] = rsqrtf((float)(hist[t] + 1));
    if (t == 0) {
        int p = 0;
        for (int i = 0; i < b; ++i) p += gcur[i];
        prefix_s = p;
    }
    scn[t] = hist[t];
    __syncthreads();
#pragma unroll
    for (int off = 1; off < BW; off <<= 1) {
        const int v = (t >= off) ? scn[t - off] : 0;
        __syncthreads();
        scn[t] += v;
        __syncthreads();
    }
    const int prefix = prefix_s;
    const int ebase = scn[t] - hist[t];
    if (r0 + t < N) rowptr[r0 + t] = prefix + ebase;
    if (b == nb - 1 && t == 0) rowptr[N] = E;
    __syncthreads();
    for (int j = t; j < Mb; j += 512) {
        const int pk = eb[j];
        const int dl = pk >> 17;
        const int pos = atomicAdd(&fillc[dl], 1);
        col[prefix + (scn[dl] - hist[dl]) + pos] = pk & 0x1FFFF;
    }
}

// agg[i,:] = hs[i,:] + sum_{j in row i} hs[col[j],:]  (bf16 in, f32 out)
__global__ __launch_bounds__(256) void gather_bf(
    const int* __restrict__ rowptr, const int* __restrict__ col,
    const unsigned short* __restrict__ hs, float* __restrict__ agg, int N)
{
    const int row = blockIdx.x * 4 + (threadIdx.x >> 6);
    if (row >= N) return;
    const int c2 = (threadIdx.x & 63) * 2;
    const size_t rb = (size_t)row * C + c2;
    float a0, a1;
    { ushort2 u = *(const ushort2*)&hs[rb]; a0 = bf2f(u.x); a1 = bf2f(u.y); }
    const int jb = rowptr[row], je = rowptr[row + 1];
    int j = jb;
    for (; j + 4 <= je; j += 4) {
        const int s0 = col[j], s1 = col[j + 1], s2 = col[j + 2], s3 = col[j + 3];
        const ushort2 u0 = *(const ushort2*)&hs[(size_t)s0 * C + c2];
        const ushort2 u1 = *(const ushort2*)&hs[(size_t)s1 * C + c2];
        const ushort2 u2 = *(const ushort2*)&hs[(size_t)s2 * C + c2];
        const ushort2 u3 = *(const ushort2*)&hs[(size_t)s3 * C + c2];
        a0 += bf2f(u0.x) + bf2f(u1.x) + bf2f(u2.x) + bf2f(u3.x);
        a1 += bf2f(u0.y) + bf2f(u1.y) + bf2f(u2.y) + bf2f(u3.y);
    }
    for (; j < je; ++j) {
        const ushort2 u = *(const ushort2*)&hs[(size_t)col[j] * C + c2];
        a0 += bf2f(u.x); a1 += bf2f(u.y);
    }
    *(float2*)&agg[rb] = make_float2(a0, a1);
}

__global__ void bn_stats_kernel(const float* __restrict__ bnacc, float* __restrict__ bnout,
                                float invN)
{
    const int c = threadIdx.x;
    const float mean = bnacc[c] * invN;
    float var = bnacc[128 + c] * invN - mean * mean;
    var = fmaxf(var, 0.f);
    bnout[c] = mean;
    bnout[128 + c] = rsqrtf(var + 1e-5f);
}

__global__ void bn_apply_kernel(const float* __restrict__ H2f, const float* __restrict__ bnp,
                                float* __restrict__ out, long long total)
{
    long long i = blockIdx.x * (long long)blockDim.x + threadIdx.x;
    const long long st = (long long)gridDim.x * blockDim.x;
    for (; i < total; i += st) {
        const int c = (int)(i & 127);
        out[i] = (H2f[i] - bnp[c]) * bnp[128 + c];
    }
}

// ---------------------------------------------------------------------------
extern "C" void kernel_launch(void* const* d_in, const int* in_sizes, int n_in,
                              void* d_out, int out_size, void* d_ws, size_t ws_size,
                              hipStream_t stream)
{
    const void* nf    = d_in[0];
    const int*  ei    = (const int*)d_in[1];
    const void* xp1   = d_in[2];
    const void* xp2   = d_in[3];
    const void* ts    = d_in[4];
    const void* freq  = d_in[5];
    const void* phase = d_in[6];
    const void* mW    = d_in[7];
    const void* mb    = d_in[8];
    const void* W1    = d_in[9];
    const void* b1    = d_in[10];
    const void* g1Wih = d_in[11];
    const void* g1Whh = d_in[12];
    const void* g1bih = d_in[13];
    const void* g1bhh = d_in[14];
    const void* W2    = d_in[15];
    const void* b2    = d_in[16];
    const void* g2Wih = d_in[17];
    const void* g2Whh = d_in[18];
    const void* g2bih = d_in[19];
    const void* g2bhh = d_in[20];
    const void* skW   = d_in[21];
    const void* skb   = d_in[22];

    const int N = in_sizes[0] / C;
    const int E = in_sizes[1] / 2;
    float* out = (float*)d_out;

    const int nb  = (N + BW - 1) >> BSH;
    const int cap = E / nb + E / (4 * nb) + 1024;

    char* w = (char*)d_ws;
    const size_t NBH = (size_t)N * C * 2;
    const size_t NBF = (size_t)N * C * 4;
    const size_t NG  = (size_t)N * 384 * 2;

    unsigned short* xbf    = (unsigned short*)(w);
    unsigned short* hsbf   = (unsigned short*)(w + NBH);
    unsigned short* H1bf   = (unsigned short*)(w + 2 * NBH);
    unsigned short* skipbf = (unsigned short*)(w + 3 * NBH);
    float* agg  = (float*)(w + 4 * NBH);
    unsigned short* G1 = (unsigned short*)(w + 4 * NBH + NBF);       // [N,384] bf16
    float* H2f  = (float*)(w + 4 * NBH + NBF + NG);
    unsigned short* Wcat1 = (unsigned short*)(w + 4 * NBH + 2 * NBF + NG);
    unsigned short* Wcat2 = Wcat1 + 384 * 256;
    float* bcat1 = (float*)(Wcat2 + 384 * 256);
    float* bcat2 = bcat1 + 384;
    float* dinv  = bcat2 + 384;
    float* bn    = dinv + N;                                  // 512 floats
    int* eflag   = (int*)(bn + 512);
    int* dtflag  = eflag + 1;
    int* gcur    = dtflag + 1;                                // 128
    int* rowptr  = gcur + 128;                                // N+1
    int* col     = rowptr + N + 1;                            // E
    int* bucketbuf = col + E;                                 // nb*cap

    const dim3 blk(256);
    const int gx = (N + 127) / 128;
    const long long totNC = (long long)N * C;

    // probes + bucketed CSR build + weight prep
    probe_kernel<<<1, 64, 0, stream>>>(ei, (const unsigned int*)freq, eflag, dtflag);
    init_kernel<<<1, 256, 0, stream>>>(gcur, bn);
    part_kernel<<<512, blk, 0, stream>>>(ei, E, cap, gcur, bucketbuf, eflag);
    bucket_csr_kernel<<<nb, 512, 0, stream>>>(bucketbuf, gcur, cap, nb, N, E,
                                              rowptr, col, dinv);
    prep_kernel<<<384, 256, 0, stream>>>(g1Wih, g1Whh, g1bih, g1bhh, Wcat1, bcat1, dtflag);
    prep_kernel<<<384, 256, 0, stream>>>(g2Wih, g2Whh, g2bih, g2bhh, Wcat2, bcat2, dtflag);

    // x = [nf | cos(ts*freq+phase)] @ mW^T + mb        -> bf16
    gemm_mfma<256, 128, 2, 0, 0, 0, 0, false, true><<<dim3(gx, 1), blk, 0, stream>>>(
        nf, mW, mb, xbf, N, nullptr, nullptr, ts, freq, phase, dtflag, 0, 0,
        nullptr, nullptr, nullptr, nullptr, nullptr);

    // --- layer 1 ---
    gemm_mfma<128, 128, 0, 2, 0, 0, 0, true, true><<<dim3(gx, 1), blk, 0, stream>>>(
        xbf, W1, nullptr, hsbf, N, dinv, nullptr, nullptr, nullptr, nullptr, dtflag, 0, 0,
        nullptr, nullptr, nullptr, nullptr, nullptr);                                   // hs1
    gather_bf<<<(N + 3) / 4, blk, 0, stream>>>(rowptr, col, hsbf, agg, N);              // agg1
    gemm_mfma<256, 384, 3, 1, 1, 1, 0, false, true><<<dim3(gx, 3), blk, 0, stream>>>(
        agg, Wcat1, bcat1, G1, N, dinv, b1, xp1, nullptr, nullptr, dtflag, 0, 0,
        nullptr, nullptr, nullptr, nullptr, nullptr);                                   // G1 = [rsum|zsum|h_n]
    gemm_mfma<128, 128, 1, 1, 0, 0, 1, false, true><<<dim3(gx, 1), blk, 0, stream>>>(
        agg, g1Wih, g1bih, H1bf, N, dinv, b1, nullptr, nullptr, nullptr, dtflag, 256, 256,
        G1, xp1, nullptr, out, nullptr);                                                // i_n + GRU + relu

    // --- layer 2 ---
    gemm_mfma<128, 128, 0, 2, 0, 0, 0, true, true><<<dim3(gx, 1), blk, 0, stream>>>(
        H1bf, W2, nullptr, hsbf, N, dinv, nullptr, nullptr, nullptr, nullptr, dtflag, 0, 0,
        nullptr, nullptr, nullptr, nullptr, nullptr);                                   // hs2
    gather_bf<<<(N + 3) / 4, blk, 0, stream>>>(rowptr, col, hsbf, agg, N);              // agg2
    gemm_mfma<128, 128, 0, 2, 0, 0, 0, false, true><<<dim3(gx, 1), blk, 0, stream>>>(
        xbf, skW, skb, skipbf, N, nullptr, nullptr, nullptr, nullptr, nullptr, dtflag, 0, 0,
        nullptr, nullptr, nullptr, nullptr, nullptr);                                   // skip
    gemm_mfma<256, 384, 3, 1, 1, 1, 0, false, true><<<dim3(gx, 3), blk, 0, stream>>>(
        agg, Wcat2, bcat2, G1, N, dinv, b2, xp2, nullptr, nullptr, dtflag, 0, 0,
        nullptr, nullptr, nullptr, nullptr, nullptr);                                   // G1 = [rsum|zsum|h_n]
    gemm_mfma<128, 128, 1, 1, 0, 0, 2, false, false><<<dim3(gx, 1), blk, 0, stream>>>(
        agg, g2Wih, g2bih, H2f, N, dinv, b2, nullptr, nullptr, nullptr, dtflag, 256, 256,
        G1, xp2, skipbf, nullptr, bn);                                                  // i_n + GRU + skip + BN stats

    bn_stats_kernel<<<1, 128, 0, stream>>>(bn, bn + 256, 1.0f / (float)N);
    bn_apply_kernel<<<4096, blk, 0, stream>>>(H2f, bn + 256, out + (size_t)N * C, totNC);
}